// Round 10
// baseline (435.770 us; speedup 1.0000x reference)
//
#include <hip/hip_runtime.h>

#define NUM_CODES 1296
#define DDIM 64
#define NUM_Q 131072      // 32*64*64
#define KC 8              // k-chunk staged in LDS
#define SELD 776          // se row pitch (768 + 8)
#define QW 8              // queries per wave (x in SGPRs)
#define THREADS 256       // 4 waves
#define QPB (QW * 4)      // 32 queries per block

// Embedding norms ||e||^2, numpy pairwise (8-accumulator) order, contraction off.
__global__ void vq_enorm(const float* __restrict__ emb, float* __restrict__ norms) {
    int k = blockIdx.x * blockDim.x + threadIdx.x;
    if (k >= NUM_CODES) return;
    const float* e = emb + (size_t)k * DDIM;
    {
#pragma clang fp contract(off)
        float r[8];
#pragma unroll
        for (int j = 0; j < 8; ++j) { float t = e[j] * e[j]; r[j] = t; }
#pragma unroll
        for (int i = 1; i < 8; ++i) {
#pragma unroll
            for (int j = 0; j < 8; ++j) { float t = e[i*8+j] * e[i*8+j]; r[j] += t; }
        }
        norms[k] = ((r[0]+r[1])+(r[2]+r[3])) + ((r[4]+r[5])+(r[6]+r[7]));
    }
}

// ||x||^2 per query, same numpy pairwise order as vq_enorm.
__global__ __launch_bounds__(256) void vq_xnorm(const float* __restrict__ x,
                                                float* __restrict__ xnorm) {
    int q = blockIdx.x * 256 + threadIdx.x;
    const float* r = x + (size_t)q * DDIM;
    float f[DDIM];
#pragma unroll
    for (int i = 0; i < DDIM/4; ++i) {
        float4 v = *(const float4*)(r + 4*i);
        f[4*i+0]=v.x; f[4*i+1]=v.y; f[4*i+2]=v.z; f[4*i+3]=v.w;
    }
    {
#pragma clang fp contract(off)
        float r8[8];
#pragma unroll
        for (int j = 0; j < 8; ++j) { float t = f[j]*f[j]; r8[j] = t; }
#pragma unroll
        for (int i = 1; i < 8; ++i) {
#pragma unroll
            for (int j = 0; j < 8; ++j) { float t = f[i*8+j]*f[i*8+j]; r8[j] += t; }
        }
        xnorm[q] = ((r8[0]+r8[1])+(r8[2]+r8[3])) + ((r8[4]+r8[5])+(r8[6]+r8[7]));
    }
}

// One N-sweep over 64*TN codes starting at tb. x values are wave-uniform
// (scalar loads); e-fragments per-lane from LDS. acc order: k ascending ==
// reference fmaf chain. Merge into best/bbk (tiles ascending -> tie keeps low k).
template<int TN>
__device__ __forceinline__ void vq_sweep(
        const float* __restrict__ x, const float* __restrict__ emb,
        const float* __restrict__ norms, const float* __restrict__ xnorm,
        float (&se)[KC][SELD], int qbu, int lane, int tid, int tb,
        float* best, int* bbk) {
    // per-lane code-norm regs (masked codes -> +inf)
    float sn[TN];
#pragma unroll
    for (int j = 0; j < TN; ++j) {
        int kg = tb + lane*TN + j;
        int kcl = kg > NUM_CODES-1 ? NUM_CODES-1 : kg;
        float nv = norms[kcl];
        sn[j] = (kg < NUM_CODES) ? nv : __builtin_inff();
    }

    float acc[QW][TN];
#pragma unroll
    for (int q = 0; q < QW; ++q)
#pragma unroll
        for (int j = 0; j < TN; ++j) acc[q][j] = 0.f;

    const int NCOL = 64 * TN;
    for (int kc = 0; kc < DDIM/KC; ++kc) {
        __syncthreads();   // previous chunk (or tile) fully consumed
        // stage se[k][c] = emb[clamp(tb+c)][kc*8 + k]
        for (int idx = tid; idx < NCOL*2; idx += THREADS) {
            int c = idx >> 1, j4 = idx & 1;
            int cg = tb + c; if (cg > NUM_CODES-1) cg = NUM_CODES-1;
            float4 v = *(const float4*)(emb + (size_t)cg*DDIM + kc*KC + j4*4);
            se[4*j4+0][c] = v.x; se[4*j4+1][c] = v.y;
            se[4*j4+2][c] = v.z; se[4*j4+3][c] = v.w;
        }
        __syncthreads();

        // wave-uniform x chunk: scalar loads (qbu readfirstlane'd, const offsets)
        float xs[KC][QW];
#pragma unroll
        for (int q = 0; q < QW; ++q) {
            const float* xr = x + (size_t)(qbu + q) * DDIM + kc*KC;
#pragma unroll
            for (int k = 0; k < KC; ++k) xs[k][q] = xr[k];
        }

#pragma unroll
        for (int k = 0; k < KC; ++k) {
            float bv[TN];
            if constexpr (TN == 12) {
                const float* bp = &se[k][lane*12];   // 48B stride: bank-uniform, 16B-aligned
                float4 v0 = *(const float4*)(bp);
                float4 v1 = *(const float4*)(bp + 4);
                float4 v2 = *(const float4*)(bp + 8);
                bv[0]=v0.x; bv[1]=v0.y; bv[2]=v0.z; bv[3]=v0.w;
                bv[4]=v1.x; bv[5]=v1.y; bv[6]=v1.z; bv[7]=v1.w;
                bv[8]=v2.x; bv[9]=v2.y; bv[10]=v2.z; bv[11]=v2.w;
            } else {
#pragma unroll
                for (int j = 0; j < TN; ++j) bv[j] = se[k][lane*TN + j];
            }
#pragma unroll
            for (int q = 0; q < QW; ++q)
#pragma unroll
                for (int j = 0; j < TN; ++j)
                    acc[q][j] = fmaf(xs[k][q], bv[j], acc[q][j]);  // k ascending
        }
    }

    // epilogue: per-query argmin over this sweep, merge into running best
#pragma unroll
    for (int q = 0; q < QW; ++q) {
        float x1 = xnorm[qbu + q];
        float b = __builtin_inff(); int bk = 0;
#pragma unroll
        for (int j = 0; j < TN; ++j) {
            float dist = (x1 + sn[j]) - 2.0f * acc[q][j];
            int kg = tb + lane*TN + j;
            if (dist < b) { b = dist; bk = kg; }      // strict < : lowest index
        }
#pragma unroll
        for (int m = 1; m < 64; m <<= 1) {
            float ob = __shfl_xor(b, m, 64);
            int  ok = __shfl_xor(bk, m, 64);
            if (ob < b || (ob == b && ok < bk)) { b = ob; bk = ok; }
        }
        if (b < best[q]) { best[q] = b; bbk[q] = bk; } // strict < : earlier tile wins ties
    }
}

__global__ __launch_bounds__(THREADS) void vq_main(
        const float* __restrict__ x, const float* __restrict__ emb,
        const float* __restrict__ norms, const float* __restrict__ xnorm,
        float* __restrict__ out) {
    __shared__ float se[KC][SELD];     // 24832 B
    const int tid = threadIdx.x;
    const int lane = tid & 63;
    const int wid = tid >> 6;
    const int qb = blockIdx.x * QPB + wid * QW;
    const int qbu = __builtin_amdgcn_readfirstlane(qb);

    float best[QW]; int bbk[QW];
#pragma unroll
    for (int q = 0; q < QW; ++q) { best[q] = __builtin_inff(); bbk[q] = 0; }

    vq_sweep<12>(x, emb, norms, xnorm, se, qbu, lane, tid, 0,   best, bbk);  // codes 0..767
    vq_sweep<9>(x, emb, norms, xnorm, se, qbu, lane, tid, 768, best, bbk);   // codes 768..1343 (masked >=1296)

    // outputs: codes as float values + gathered embedding rows
#pragma unroll
    for (int q = 0; q < QW; ++q) {
        int kk = bbk[q];                // identical in all lanes after butterfly
        if (lane == 0) out[qbu + q] = (float)kk;
        if (lane < 16)
            *(float4*)(out + (size_t)NUM_Q + (size_t)(qbu + q)*DDIM + lane*4) =
                *(const float4*)(emb + (size_t)kk*DDIM + lane*4);
    }
}

extern "C" void kernel_launch(void* const* d_in, const int* in_sizes, int n_in,
                              void* d_out, int out_size, void* d_ws, size_t ws_size,
                              hipStream_t stream) {
    const float* x   = (const float*)d_in[0];
    const float* emb = (const float*)d_in[1];
    float* norms = (float*)d_ws;                       // 5184 B
    float* xnorm = (float*)((char*)d_ws + 8192);       // 512 KB

    hipLaunchKernelGGL(vq_enorm, dim3((NUM_CODES + 255) / 256), dim3(256), 0, stream,
                       emb, norms);
    hipLaunchKernelGGL(vq_xnorm, dim3(NUM_Q / 256), dim3(256), 0, stream,
                       x, xnorm);
    hipLaunchKernelGGL(vq_main, dim3(NUM_Q / QPB), dim3(THREADS), 0, stream,
                       x, emb, norms, xnorm, (float*)d_out);
}

// Round 11
// 432.691 us; speedup vs baseline: 1.0071x; 1.0071x over previous
//
#include <hip/hip_runtime.h>
#include <hip/hip_fp16.h>

#define NUM_CODES 1296
#define DDIM 64
#define NUM_Q 131072      // 32*64*64
#define NTILE 81          // 1296 = 81 * 16, no tail
#define THREADS 256       // 4 waves
#define QPB 16            // queries per block; 131072 = 8192 * 16
#define SP 20             // sS pitch in halfwords (16 q + 4 pad: b64-aligned, 2-way banks)
#define MARGIN 0.08f      // >= 2*(chain err ~1e-4) + 2*(mfma split+accum+fp16 store ~0.018)

typedef __attribute__((ext_vector_type(8))) short bf16x8;
typedef __attribute__((ext_vector_type(4))) float f32x4;

__device__ __forceinline__ ushort f2bf(float f) {          // fp32 -> bf16 RNE (finite)
    unsigned u = __float_as_uint(f);
    return (ushort)((u + 0x7fffu + ((u >> 16) & 1u)) >> 16);
}
__device__ __forceinline__ float bf2f(ushort h) {
    return __uint_as_float(((unsigned)h) << 16);
}

// enorm (exact numpy pairwise chain) + bf16 hi/lo split of embeddings.
__global__ __launch_bounds__(64) void vq_prep(const float* __restrict__ emb,
                                              float* __restrict__ enorm,
                                              ushort* __restrict__ eh,
                                              ushort* __restrict__ el) {
    int k = blockIdx.x * 64 + threadIdx.x;
    if (k >= NUM_CODES) return;
    const float* e = emb + (size_t)k * DDIM;
    float f[DDIM];
#pragma unroll
    for (int i = 0; i < 16; ++i) {
        float4 v = *(const float4*)(e + 4 * i);
        f[4*i] = v.x; f[4*i+1] = v.y; f[4*i+2] = v.z; f[4*i+3] = v.w;
    }
    {
#pragma clang fp contract(off)
        float r8[8];
#pragma unroll
        for (int j = 0; j < 8; ++j) { float t = f[j] * f[j]; r8[j] = t; }
#pragma unroll
        for (int i = 1; i < 8; ++i) {
#pragma unroll
            for (int j = 0; j < 8; ++j) { float t = f[i*8+j] * f[i*8+j]; r8[j] += t; }
        }
        enorm[k] = ((r8[0]+r8[1])+(r8[2]+r8[3])) + ((r8[4]+r8[5])+(r8[6]+r8[7]));
    }
    ushort hh[DDIM], ll[DDIM];
#pragma unroll
    for (int d = 0; d < DDIM; ++d) {
        ushort hb = f2bf(f[d]);
        hh[d] = hb;
        ll[d] = f2bf(f[d] - bf2f(hb));
    }
    uint* dh = (uint*)(eh + (size_t)k * DDIM);
    uint* dl = (uint*)(el + (size_t)k * DDIM);
#pragma unroll
    for (int i = 0; i < 32; ++i) {
        dh[i] = (uint)hh[2*i] | ((uint)hh[2*i+1] << 16);
        dl[i] = (uint)ll[2*i] | ((uint)ll[2*i+1] << 16);
    }
}

// ||x||^2 per query, exact numpy pairwise chain (for the rescore formula).
__global__ __launch_bounds__(256) void vq_xnorm(const float* __restrict__ x,
                                                float* __restrict__ xnorm) {
    int q = blockIdx.x * 256 + threadIdx.x;
    const float* r = x + (size_t)q * DDIM;
    float f[DDIM];
#pragma unroll
    for (int i = 0; i < 16; ++i) {
        float4 v = *(const float4*)(r + 4 * i);
        f[4*i] = v.x; f[4*i+1] = v.y; f[4*i+2] = v.z; f[4*i+3] = v.w;
    }
    {
#pragma clang fp contract(off)
        float r8[8];
#pragma unroll
        for (int j = 0; j < 8; ++j) { float t = f[j] * f[j]; r8[j] = t; }
#pragma unroll
        for (int i = 1; i < 8; ++i) {
#pragma unroll
            for (int j = 0; j < 8; ++j) { float t = f[i*8+j] * f[i*8+j]; r8[j] += t; }
        }
        xnorm[q] = ((r8[0]+r8[1])+(r8[2]+r8[3])) + ((r8[4]+r8[5])+(r8[6]+r8[7]));
    }
}

// MFMA bf16-split screen + exact fp32 rescore of the certified candidate set.
__global__ __launch_bounds__(THREADS) void vq_main(
        const float* __restrict__ x, const float* __restrict__ emb,
        const float* __restrict__ enorm, const float* __restrict__ xnorm,
        const ushort* __restrict__ eh, const ushort* __restrict__ el,
        float* __restrict__ out) {
    __shared__ ushort sS[NUM_CODES * SP];   // 51840 B: screened s~ (fp16), [c][q]
    __shared__ float scr[64];               // per-wave rmin, [w][q]
    const int tid  = threadIdx.x;
    const int lane = tid & 63;
    const int w    = tid >> 6;              // wave 0..3
    const int cl   = lane & 15;
    const int g    = lane >> 4;             // k-group / D-row group
    const int qb   = blockIdx.x * QPB;

    // ---- A-frags (persistent): query row qb+cl, k in [g*8,g*8+8) and +32 ----
    bf16x8 xh0, xl0, xh1, xl1;
    {
        const float* xp = x + (size_t)(qb + cl) * DDIM + g * 8;
#pragma unroll
        for (int j = 0; j < 8; ++j) {
            float f0 = xp[j], f1 = xp[j + 32];
            ushort h0 = f2bf(f0);
            xh0[j] = (short)h0; xl0[j] = (short)f2bf(f0 - bf2f(h0));
            ushort h1 = f2bf(f1);
            xh1[j] = (short)h1; xl1[j] = (short)f2bf(f1 - bf2f(h1));
        }
    }

    float rmin[4];
#pragma unroll
    for (int r = 0; r < 4; ++r) rmin[r] = __builtin_inff();

    // ---- pass A: waves split the 81 c-tiles ----
    for (int ci = w; ci < NTILE; ci += 4) {
        const int c = ci * 16 + cl;         // this lane's code (B-frag col)
        const ushort* ep = eh + (size_t)c * DDIM + g * 8;
        const ushort* lp = el + (size_t)c * DDIM + g * 8;
        bf16x8 bh0 = *(const bf16x8*)ep;
        bf16x8 bh1 = *(const bf16x8*)(ep + 32);
        bf16x8 bl0 = *(const bf16x8*)lp;
        bf16x8 bl1 = *(const bf16x8*)(lp + 32);
        float x2c = enorm[c];

        f32x4 a0 = {0.f, 0.f, 0.f, 0.f};
        f32x4 a1 = {0.f, 0.f, 0.f, 0.f};
        a0 = __builtin_amdgcn_mfma_f32_16x16x32_bf16(xh0, bh0, a0, 0, 0, 0); // h.h
        a0 = __builtin_amdgcn_mfma_f32_16x16x32_bf16(xh1, bh1, a0, 0, 0, 0);
        a1 = __builtin_amdgcn_mfma_f32_16x16x32_bf16(xl0, bh0, a1, 0, 0, 0); // l.h
        a1 = __builtin_amdgcn_mfma_f32_16x16x32_bf16(xl1, bh1, a1, 0, 0, 0);
        a0 = __builtin_amdgcn_mfma_f32_16x16x32_bf16(xh0, bl0, a0, 0, 0, 0); // h.l
        a0 = __builtin_amdgcn_mfma_f32_16x16x32_bf16(xh1, bl1, a0, 0, 0, 0);

        // D: col = lane&15 (code), row = g*4 + r (query)
        ushort4 pk;
#pragma unroll
        for (int r = 0; r < 4; ++r) {
            float s = fmaf(-2.f, a0[r] + a1[r], x2c);   // screen = x2 - 2*dot~
            rmin[r] = fminf(rmin[r], s);
            ((ushort*)&pk)[r] = __half_as_ushort(__float2half(s));
        }
        *(ushort4*)&sS[c * SP + g * 4] = pk;            // byte 40c+8g: aligned, 2-way banks
    }

    // rmin across the 16 cols of this wave
#pragma unroll
    for (int m = 1; m < 16; m <<= 1) {
#pragma unroll
        for (int r = 0; r < 4; ++r)
            rmin[r] = fminf(rmin[r], __shfl_xor(rmin[r], m, 64));
    }
    if (cl == 0) {
#pragma unroll
        for (int r = 0; r < 4; ++r) scr[w * 16 + g * 4 + r] = rmin[r];
    }
    __syncthreads();

    // ---- pass B: wave w handles queries 4w..4w+3 ----
    for (int qi = 0; qi < 4; ++qi) {
        const int q = w * 4 + qi;
        const size_t gq = (size_t)qb + q;
        const float thr = fminf(fminf(scr[q], scr[16 + q]),
                                fminf(scr[32 + q], scr[48 + q])) + MARGIN;

        int nh = 0, firstc = 0;
#pragma unroll
        for (int t = 0; t < 21; ++t) {
            int c = lane + (t << 6);
            bool hit = (c < NUM_CODES) &&
                       (__half2float(__ushort_as_half(sS[c * SP + q])) <= thr);
            unsigned long long m = __ballot(hit);
            if (m != 0ULL) {
                if (nh == 0) firstc = (t << 6) + (__ffsll(m) - 1);
                nh += __popcll(m);
            }
        }

        int bk;
        if (nh == 1) {
            bk = firstc;    // certified: true argmin is in S, |S|=1 -> done, no fp compare
        } else {
            const float xnq = xnorm[gq];
            float bex = __builtin_inff(); int bc = 0x7fffffff;
            for (int t = 0; t < 21; ++t) {
                int c = lane + (t << 6);
                bool hit = (c < NUM_CODES) &&
                           (__half2float(__ushort_as_half(sS[c * SP + q])) <= thr);
                if (hit) {
                    // exact reference chain: d-ascending fmaf, (x1+x2) - 2*dot
                    const float* er = emb + (size_t)c * DDIM;
                    const float* xr = x + gq * DDIM;
                    float dot = 0.f;
#pragma unroll
                    for (int p = 0; p < 16; ++p) {
                        float4 ev = *(const float4*)(er + 4 * p);
                        float4 xv = *(const float4*)(xr + 4 * p);
                        dot = fmaf(xv.x, ev.x, dot); dot = fmaf(xv.y, ev.y, dot);
                        dot = fmaf(xv.z, ev.z, dot); dot = fmaf(xv.w, ev.w, dot);
                    }
                    float dist = (xnq + enorm[c]) - 2.f * dot;
                    if (dist < bex) { bex = dist; bc = c; }   // lane's c ascends: strict <
                }
            }
#pragma unroll
            for (int m2 = 1; m2 < 64; m2 <<= 1) {
                float ob = __shfl_xor(bex, m2, 64);
                int  oc = __shfl_xor(bc, m2, 64);
                if (ob < bex || (ob == bex && oc < bc)) { bex = ob; bc = oc; }
            }
            bk = bc;
        }

        if (lane == 0) out[gq] = (float)bk;             // codes as float values
        if (lane < 16)
            *(float4*)(out + (size_t)NUM_Q + gq * DDIM + lane * 4) =
                *(const float4*)(emb + (size_t)bk * DDIM + lane * 4);
    }
}

extern "C" void kernel_launch(void* const* d_in, const int* in_sizes, int n_in,
                              void* d_out, int out_size, void* d_ws, size_t ws_size,
                              hipStream_t stream) {
    const float* x   = (const float*)d_in[0];
    const float* emb = (const float*)d_in[1];
    float*  enorm = (float*)d_ws;                          // 5184 B (pad to 8192)
    float*  xnorm = (float*)((char*)d_ws + 8192);          // 524288 B
    ushort* eh    = (ushort*)((char*)d_ws + 532480);       // 165888 B
    ushort* el    = (ushort*)((char*)d_ws + 698368);       // 165888 B

    hipLaunchKernelGGL(vq_prep, dim3((NUM_CODES + 63) / 64), dim3(64), 0, stream,
                       emb, enorm, eh, el);
    hipLaunchKernelGGL(vq_xnorm, dim3(NUM_Q / 256), dim3(256), 0, stream,
                       x, xnorm);
    hipLaunchKernelGGL(vq_main, dim3(NUM_Q / QPB), dim3(THREADS), 0, stream,
                       x, emb, enorm, xnorm, eh, el, (float*)d_out);
}

// Round 12
// 181.423 us; speedup vs baseline: 2.4020x; 2.3850x over previous
//
#include <hip/hip_runtime.h>

#define NUM_CODES 1296
#define DDIM 64
#define NUM_Q 131072      // 32*64*64
#define NTILE 81          // 1296 = 81 * 16, no tail
#define THREADS 256       // 4 waves
#define QPW 32            // queries per wave (2 MFMA row-fragments)
#define QPB 128           // queries per block; 1024 blocks
#define MARGIN 0.25f      // certified: 2*alpha <= 0.11 (bf16 screen), 2.3x headroom
#define CAP 512           // per-wave candidate queue (expect ~50)

typedef __attribute__((ext_vector_type(8))) short bf16x8;
typedef __attribute__((ext_vector_type(4))) float f32x4;

__device__ __forceinline__ ushort f2bf(float f) {   // fp32 -> bf16 RNE
    unsigned u = __float_as_uint(f);
    return (ushort)((u + 0x7fffu + ((u >> 16) & 1u)) >> 16);
}

// enorm (exact numpy pairwise chain) + bf16 embeddings.
__global__ __launch_bounds__(64) void vq_prep(const float* __restrict__ emb,
                                              float* __restrict__ enorm,
                                              ushort* __restrict__ eh) {
    int k = blockIdx.x * 64 + threadIdx.x;
    if (k >= NUM_CODES) return;
    const float* e = emb + (size_t)k * DDIM;
    float f[DDIM];
#pragma unroll
    for (int i = 0; i < 16; ++i) {
        float4 v = *(const float4*)(e + 4 * i);
        f[4*i] = v.x; f[4*i+1] = v.y; f[4*i+2] = v.z; f[4*i+3] = v.w;
    }
    {
#pragma clang fp contract(off)
        float r8[8];
#pragma unroll
        for (int j = 0; j < 8; ++j) { float t = f[j] * f[j]; r8[j] = t; }
#pragma unroll
        for (int i = 1; i < 8; ++i) {
#pragma unroll
            for (int j = 0; j < 8; ++j) { float t = f[i*8+j] * f[i*8+j]; r8[j] += t; }
        }
        enorm[k] = ((r8[0]+r8[1])+(r8[2]+r8[3])) + ((r8[4]+r8[5])+(r8[6]+r8[7]));
    }
    uint* dh = (uint*)(eh + (size_t)k * DDIM);
#pragma unroll
    for (int i = 0; i < 32; ++i)
        dh[i] = (uint)f2bf(f[2*i]) | ((uint)f2bf(f[2*i+1]) << 16);
}

// ||x||^2 per query, exact numpy pairwise chain (for the rescore formula).
__global__ __launch_bounds__(256) void vq_xnorm(const float* __restrict__ x,
                                                float* __restrict__ xnorm) {
    int q = blockIdx.x * 256 + threadIdx.x;
    const float* r = x + (size_t)q * DDIM;
    float f[DDIM];
#pragma unroll
    for (int i = 0; i < 16; ++i) {
        float4 v = *(const float4*)(r + 4 * i);
        f[4*i] = v.x; f[4*i+1] = v.y; f[4*i+2] = v.z; f[4*i+3] = v.w;
    }
    {
#pragma clang fp contract(off)
        float r8[8];
#pragma unroll
        for (int j = 0; j < 8; ++j) { float t = f[j] * f[j]; r8[j] = t; }
#pragma unroll
        for (int i = 1; i < 8; ++i) {
#pragma unroll
            for (int j = 0; j < 8; ++j) { float t = f[i*8+j] * f[i*8+j]; r8[j] += t; }
        }
        xnorm[q] = ((r8[0]+r8[1])+(r8[2]+r8[3])) + ((r8[4]+r8[5])+(r8[6]+r8[7]));
    }
}

// bf16 MFMA screen (2 sweeps, no score storage) + exact fp32 rescore of the
// certified candidate set. Wave w owns queries [qw, qw+32).
__global__ __launch_bounds__(THREADS) void vq_main(
        const float* __restrict__ x, const float* __restrict__ emb,
        const float* __restrict__ enorm_g, const float* __restrict__ xnorm,
        const ushort* __restrict__ eh, float* __restrict__ out) {
    __shared__ float sn[NUM_CODES];                 // 5184 B
    __shared__ unsigned wq[4][CAP];                 // 8192 B
    __shared__ unsigned wcnt[4];
    __shared__ unsigned long long best64[4][QPW];   // 1024 B

    const int tid  = threadIdx.x;
    const int lane = tid & 63;
    const int w    = tid >> 6;
    const int cl   = lane & 15;          // MFMA col = code-in-tile
    const int g    = lane >> 4;          // k-slice / D-row group
    const long qw  = (long)blockIdx.x * QPB + w * QPW;

    for (int i = tid; i < NUM_CODES; i += THREADS) sn[i] = enorm_g[i];
    if (lane < QPW) best64[w][lane] = ~0ULL;
    if (lane == 0) wcnt[w] = 0;
    __syncthreads();

    // A-frags (persistent): qset0 rows qw+cl, qset1 rows qw+16+cl; k = g*8(+32)
    bf16x8 a00, a01, a10, a11;
    {
        const float* xp0 = x + (qw + cl) * DDIM + g * 8;
        const float* xp1 = xp0 + 16 * DDIM;
#pragma unroll
        for (int j = 0; j < 8; ++j) {
            a00[j] = (short)f2bf(xp0[j]);
            a01[j] = (short)f2bf(xp0[j + 32]);
            a10[j] = (short)f2bf(xp1[j]);
            a11[j] = (short)f2bf(xp1[j + 32]);
        }
    }

    float rmin0[4], rmin1[4];
#pragma unroll
    for (int r = 0; r < 4; ++r) { rmin0[r] = __builtin_inff(); rmin1[r] = __builtin_inff(); }

    const ushort* ebase = eh + (size_t)cl * DDIM + g * 8;

    // ---- sweep 1: per-query screen minimum (registers only) ----
    for (int ci = 0; ci < NTILE; ++ci) {
        const ushort* ep = ebase + (size_t)ci * (16 * DDIM);
        bf16x8 b0 = *(const bf16x8*)ep;
        bf16x8 b1 = *(const bf16x8*)(ep + 32);
        float x2c = sn[ci * 16 + cl];
        f32x4 acc0 = {0.f,0.f,0.f,0.f}, acc1 = {0.f,0.f,0.f,0.f};
        acc0 = __builtin_amdgcn_mfma_f32_16x16x32_bf16(a00, b0, acc0, 0, 0, 0);
        acc1 = __builtin_amdgcn_mfma_f32_16x16x32_bf16(a10, b0, acc1, 0, 0, 0);
        acc0 = __builtin_amdgcn_mfma_f32_16x16x32_bf16(a01, b1, acc0, 0, 0, 0);
        acc1 = __builtin_amdgcn_mfma_f32_16x16x32_bf16(a11, b1, acc1, 0, 0, 0);
#pragma unroll
        for (int r = 0; r < 4; ++r) {
            rmin0[r] = fminf(rmin0[r], fmaf(-2.f, acc0[r], x2c));
            rmin1[r] = fminf(rmin1[r], fmaf(-2.f, acc1[r], x2c));
        }
    }
    // reduce over the 16 cols (codes) of each g-group; rows (queries) stay per-lane
#pragma unroll
    for (int m = 1; m < 16; m <<= 1) {
#pragma unroll
        for (int r = 0; r < 4; ++r) {
            rmin0[r] = fminf(rmin0[r], __shfl_xor(rmin0[r], m, 64));
            rmin1[r] = fminf(rmin1[r], __shfl_xor(rmin1[r], m, 64));
        }
    }
#pragma unroll
    for (int r = 0; r < 4; ++r) { rmin0[r] += MARGIN; rmin1[r] += MARGIN; }  // thresholds

    // ---- sweep 2: identical recompute, enqueue certified candidates ----
    for (int ci = 0; ci < NTILE; ++ci) {
        const ushort* ep = ebase + (size_t)ci * (16 * DDIM);
        bf16x8 b0 = *(const bf16x8*)ep;
        bf16x8 b1 = *(const bf16x8*)(ep + 32);
        float x2c = sn[ci * 16 + cl];
        f32x4 acc0 = {0.f,0.f,0.f,0.f}, acc1 = {0.f,0.f,0.f,0.f};
        acc0 = __builtin_amdgcn_mfma_f32_16x16x32_bf16(a00, b0, acc0, 0, 0, 0);
        acc1 = __builtin_amdgcn_mfma_f32_16x16x32_bf16(a10, b0, acc1, 0, 0, 0);
        acc0 = __builtin_amdgcn_mfma_f32_16x16x32_bf16(a01, b1, acc0, 0, 0, 0);
        acc1 = __builtin_amdgcn_mfma_f32_16x16x32_bf16(a11, b1, acc1, 0, 0, 0);
        const int c = ci * 16 + cl;
#pragma unroll
        for (int r = 0; r < 4; ++r) {
            float s0 = fmaf(-2.f, acc0[r], x2c);
            float s1 = fmaf(-2.f, acc1[r], x2c);
            if (s0 <= rmin0[r]) {
                unsigned idx = atomicAdd(&wcnt[w], 1u);
                if (idx < CAP) wq[w][idx] = ((unsigned)(g*4 + r) << 11) | (unsigned)c;
            }
            if (s1 <= rmin1[r]) {
                unsigned idx = atomicAdd(&wcnt[w], 1u);
                if (idx < CAP) wq[w][idx] = ((unsigned)(16 + g*4 + r) << 11) | (unsigned)c;
            }
        }
    }
    __syncthreads();

    // ---- exact rescore (reference chain, bit-identical argmin) ----
    unsigned cnt = wcnt[w]; if (cnt > CAP) cnt = CAP;
    for (unsigned i = lane; i < cnt; i += 64) {
        unsigned p = wq[w][i];
        int ql = (int)(p >> 11); int c = (int)(p & 0x7FFu);
        long gq = qw + ql;
        const float* xr = x + gq * DDIM;
        const float* er = emb + (size_t)c * DDIM;
        float dot = 0.f;
#pragma unroll
        for (int p4 = 0; p4 < 16; ++p4) {
            float4 xv = *(const float4*)(xr + 4 * p4);
            float4 ev = *(const float4*)(er + 4 * p4);
            dot = fmaf(xv.x, ev.x, dot); dot = fmaf(xv.y, ev.y, dot);
            dot = fmaf(xv.z, ev.z, dot); dot = fmaf(xv.w, ev.w, dot);
        }
        float dist = (xnorm[gq] + sn[c]) - 2.f * dot;   // reference rounding order
        unsigned u = __float_as_uint(dist);
        unsigned key = (u & 0x80000000u) ? ~u : (u | 0x80000000u);  // monotone map
        unsigned long long pk = ((unsigned long long)key << 32) | (unsigned)c;
        atomicMin(&best64[w][ql], pk);   // lexicographic (dist, c): ties -> low c
    }
    __syncthreads();

    // ---- outputs: codes (as float) + gathered embedding rows ----
#pragma unroll
    for (int qq = 0; qq < 8; ++qq) {
        int ql = qq * 4 + g;
        unsigned kk = (unsigned)(best64[w][ql] & 0xFFFFFFFFu);
        long gq = qw + ql;
        if (cl == 0) out[gq] = (float)kk;
        *(float4*)(out + (long)NUM_Q + gq * DDIM + cl * 4) =
            *(const float4*)(emb + (size_t)kk * DDIM + cl * 4);
    }
}

extern "C" void kernel_launch(void* const* d_in, const int* in_sizes, int n_in,
                              void* d_out, int out_size, void* d_ws, size_t ws_size,
                              hipStream_t stream) {
    const float* x   = (const float*)d_in[0];
    const float* emb = (const float*)d_in[1];
    float*  enorm = (float*)d_ws;                      // 5184 B (pad to 8192)
    float*  xnorm = (float*)((char*)d_ws + 8192);      // 524288 B
    ushort* eh    = (ushort*)((char*)d_ws + 532480);   // 165888 B (16B-aligned)

    hipLaunchKernelGGL(vq_prep, dim3((NUM_CODES + 63) / 64), dim3(64), 0, stream,
                       emb, enorm, eh);
    hipLaunchKernelGGL(vq_xnorm, dim3(NUM_Q / 256), dim3(256), 0, stream,
                       x, xnorm);
    hipLaunchKernelGGL(vq_main, dim3(NUM_Q / QPB), dim3(THREADS), 0, stream,
                       x, emb, enorm, xnorm, eh, (float*)d_out);
}